// Round 9
// baseline (205.487 us; speedup 1.0000x reference)
//
#include <hip/hip_runtime.h>
#include <hip/hip_bf16.h>

// InfoNCE: a[4096,512], p[4096,512], n[16384,512] f32 -> 4 f32 scalars.
// R13: BKB=128 (half the iterations, same sync structure). R12 post-mortem:
//     halving per-wave LDS reads changed nothing (52.8 vs 55.2us) -> not
//     LDS-BW-bound; the ~990cyc/iter is the per-iteration sync skeleton
//     (vmcnt + s_barrier over 16 waves/CU + fences), paid 64x. Halve the
//     count: k-chunk 64->128 B, 32 iters for gemm0, per-iter work doubles
//     (2 stage loads, 8 b128 B-reads with R4's measured-zero-conflict
//     stride-128 XOR granule scheme, 32 MFMA). Ring 4x16KB=64KB -> still
//     2 blocks/CU. Counted vmcnt: 2 loads/tile, dist 2 -> vmcnt(4)/2/0.
//     A-regs unchanged in bytes (256B/lane), re-indexed af[rt][kc][t].
// ws layout: a8(2MB) p8(2MB) n8(8MB) | S[4096] csA[8192] csP[8192] csN[8192]
//            lsum[1] pad[3] cnt[4]

#define D_DIM 512
#define B_ROWS 4096
#define P_ROWS 4096
#define N_ROWS 16384
#define INV_T 14.285714285714286f
#define EPS_L 1e-8f
#define CS_STRIDE 16
#define GRID 512

typedef unsigned char fp8_t;
typedef __attribute__((ext_vector_type(4))) float floatx4;   // MFMA C/D frag
typedef __attribute__((ext_vector_type(2))) long longx2;     // 16B = 2 MFMA operands
typedef unsigned int uint32;

#define BM 128
#define BN 128
#define BKB 128  // K-elements per B tile == bytes per row per tile (fp8)
#define NBUF 4   // 4 x 16 KB ring

typedef const __attribute__((address_space(1))) unsigned int* as1_u32p;
typedef __attribute__((address_space(3))) unsigned int* as3_u32p;

__device__ __forceinline__ void load_lds16(const void* g, void* l) {
    // each lane writes 16B at (wave-uniform l) + lane*16
    __builtin_amdgcn_global_load_lds((as1_u32p)g, (as3_u32p)l, 16, 0, 0);
}

// ---- fused: L2-normalize rows -> fp8 e4m3, and accumulate fp32 column sums ----
// grid = 1024 blocks x 256 thr. Segments: b<256 -> A, b<512 -> P, else -> N.
__global__ __launch_bounds__(256) void norm_colsum(
        const float* __restrict__ a, const float* __restrict__ p, const float* __restrict__ n,
        fp8_t* __restrict__ a8, fp8_t* __restrict__ p8, fp8_t* __restrict__ n8,
        float* __restrict__ csA, float* __restrict__ csP, float* __restrict__ csN) {
    const float* in; fp8_t* outp; float* cs; int rows, nb, bseg;
    int b = blockIdx.x;
    if (b < 256)      { in = a; outp = a8; cs = csA; rows = B_ROWS; nb = 256; bseg = b; }
    else if (b < 512) { in = p; outp = p8; cs = csP; rows = P_ROWS; nb = 256; bseg = b - 256; }
    else              { in = n; outp = n8; cs = csN; rows = N_ROWS; nb = 512; bseg = b - 512; }

    const int wave = threadIdx.x >> 6;
    const int lane = threadIdx.x & 63;

    float cs0[4] = {0.f, 0.f, 0.f, 0.f};
    float cs1[4] = {0.f, 0.f, 0.f, 0.f};

    for (int chunk = bseg; chunk < (rows >> 2); chunk += nb) {
        int r = chunk * 4 + wave;
        const float4* rp = reinterpret_cast<const float4*>(in + (size_t)r * D_DIM);
        float4 v0 = rp[lane];
        float4 v1 = rp[lane + 64];
        float ss = v0.x*v0.x + v0.y*v0.y + v0.z*v0.z + v0.w*v0.w
                 + v1.x*v1.x + v1.y*v1.y + v1.z*v1.z + v1.w*v1.w;
#pragma unroll
        for (int off = 1; off < 64; off <<= 1) ss += __shfl_xor(ss, off);
        float inv = 1.0f / fmaxf(sqrtf(ss), 1e-12f);
        float f0x = v0.x*inv, f0y = v0.y*inv, f0z = v0.z*inv, f0w = v0.w*inv;
        float f1x = v1.x*inv, f1y = v1.y*inv, f1z = v1.z*inv, f1w = v1.w*inv;
        cs0[0] += f0x; cs0[1] += f0y; cs0[2] += f0z; cs0[3] += f0w;
        cs1[0] += f1x; cs1[1] += f1y; cs1[2] += f1z; cs1[3] += f1w;
        // pack 4 floats -> 4 fp8 e4m3 bytes (RNE hw cvt)
        int pk0 = __builtin_amdgcn_cvt_pk_fp8_f32(f0x, f0y, 0, 0);
        pk0     = __builtin_amdgcn_cvt_pk_fp8_f32(f0z, f0w, pk0, 1);
        int pk1 = __builtin_amdgcn_cvt_pk_fp8_f32(f1x, f1y, 0, 0);
        pk1     = __builtin_amdgcn_cvt_pk_fp8_f32(f1z, f1w, pk1, 1);
        uint32* op = reinterpret_cast<uint32*>(outp + (size_t)r * D_DIM);
        op[lane]      = (uint32)pk0;   // bytes 4*lane .. 4*lane+3
        op[lane + 64] = (uint32)pk1;   // bytes 256+4*lane ..
    }

    // block-level colsum reduce: LDS atomics (4-way max contention), then one
    // global atomic per column per block, spread across 64B lines.
    __shared__ float csh[D_DIM];
    if (threadIdx.x < 256) { csh[threadIdx.x] = 0.f; csh[threadIdx.x + 256] = 0.f; }
    __syncthreads();
#pragma unroll
    for (int j = 0; j < 4; ++j) {
        atomicAdd(&csh[lane * 4 + j], cs0[j]);
        atomicAdd(&csh[256 + lane * 4 + j], cs1[j]);
    }
    __syncthreads();
    if (threadIdx.x < 256) {
        atomicAdd(&cs[(size_t)threadIdx.x * CS_STRIDE], csh[threadIdx.x]);
        atomicAdd(&cs[(size_t)(threadIdx.x + 256) * CS_STRIDE], csh[threadIdx.x + 256]);
    }
}

// ---- gemm phase body: A in regs (32 rows/wave), B 4-ring LDS (BKB=128),
// 1 barrier/iter, 32 MFMA/iter. Wave grid 4(M: wr) x 2(N: wc).
// EPI==0: S[row] += sum_col exp(C*invT); EPI==1: lsum over -log(pe/(pe+S)+eps).
template <int EPI, int TN>
__device__ __forceinline__ void gemm_body(const fp8_t* __restrict__ A,
                                          const fp8_t* __restrict__ Bm,
                                          float* __restrict__ S,
                                          float* __restrict__ loss_sum,
                                          int m0, int nt0, int tid,
                                          fp8_t (*Bl)[BN * BKB], float* csh) {
    const int lane = tid & 63;
    const int w    = tid >> 6;      // 0..7
    const int wr   = w >> 1;        // 0..3: 32-row band
    const int wc   = w & 1;         // 0..1: 64-col half
    const int lr   = lane & 15;
    const int q    = lane >> 4;

    // A fragments: rows m0+wr*32+{lr,16+lr}; for k-chunk kc, sub-chunk t:
    // true bytes [kc*128 + t*64 + q*16, +16) -- matches B's granule mapping
    // (per-(q,t,half) true-k identical on both sides -> exact dot product).
    longx2 af[2][4][2];
#pragma unroll
    for (int rt = 0; rt < 2; ++rt) {
        const fp8_t* arow = A + (size_t)(m0 + wr * 32 + rt * 16 + lr) * D_DIM + q * 16;
#pragma unroll
        for (int kc = 0; kc < 4; ++kc)
#pragma unroll
            for (int t = 0; t < 2; ++t)
                af[rt][kc][t] = *reinterpret_cast<const longx2*>(arow + kc * 128 + t * 64);
    }

    // B staging (R4/R6's measured-zero-conflict scheme, stride 128):
    // LDS[r*128 + s*16] holds true granule s^(r&7) of row r. Lane l covers
    // row rbase+(l>>3), slot l&7; 8-aligned rbase -> source granule
    // (l&7)^(l>>3). Two 1KB calls per wave per tile (rows w*16.. and +8).
    const int srow = lane >> 3;                      // 0..7
    const int sg   = (lane & 7) ^ srow;              // inverse-swizzled source granule
    const fp8_t* bbase = Bm + (size_t)(nt0 * BN + w * 16 + srow) * D_DIM + sg * 16;
    // fragment read: lane wants true granule g=t*4+q of row r -> slot g^(r&7)

    auto stage = [&](int tt) {   // tt = n-tile*4 + kc
        const fp8_t* src = bbase + (size_t)(tt >> 2) * (size_t)(BN * D_DIM)
                                 + (size_t)((tt & 3) * BKB);
        load_lds16(src,             &Bl[tt & 3][(w * 16) * BKB]);
        load_lds16(src + 8 * D_DIM, &Bl[tt & 3][(w * 16 + 8) * BKB]);
    };

    float vac[2][4];
    float Sv[2][4];
    float lsum = 0.f;
    if (EPI == 0) {
#pragma unroll
        for (int rt = 0; rt < 2; ++rt)
#pragma unroll
            for (int reg = 0; reg < 4; ++reg) vac[rt][reg] = 0.f;
    } else {
#pragma unroll
        for (int rt = 0; rt < 2; ++rt)
#pragma unroll
            for (int reg = 0; reg < 4; ++reg)
                Sv[rt][reg] = S[m0 + wr * 32 + rt * 16 + q * 4 + reg];
    }

    stage(0);
    stage(1);

    for (int j = 0; j < TN; ++j) {
        floatx4 acc[2][4];
#pragma unroll
        for (int rt = 0; rt < 2; ++rt)
#pragma unroll
            for (int ct = 0; ct < 4; ++ct) acc[rt][ct] = (floatx4){0.f, 0.f, 0.f, 0.f};

#pragma unroll
        for (int kc = 0; kc < 4; ++kc) {
            const int tt = j * 4 + kc;
            if (tt < TN * 4 - 2) {
                stage(tt + 2);   // ring dist 2, depth 4: writers never collide
                asm volatile("s_waitcnt vmcnt(4)" ::: "memory");  // tile tt landed
            } else if (tt == TN * 4 - 2) {
                asm volatile("s_waitcnt vmcnt(2)" ::: "memory");
            } else {
                asm volatile("s_waitcnt vmcnt(0)" ::: "memory");
            }
            __builtin_amdgcn_sched_barrier(0);
            __builtin_amdgcn_s_barrier();   // only barrier: tile tt resident
            __builtin_amdgcn_sched_barrier(0);

            const fp8_t* bl = &Bl[tt & 3][0];
            __builtin_amdgcn_s_setprio(1);
#pragma unroll
            for (int t = 0; t < 2; ++t)
#pragma unroll
                for (int ct = 0; ct < 4; ++ct) {
                    const int r = wc * 64 + ct * 16 + lr;
                    const int off = ((((t << 2) | q) ^ (r & 7)) << 4);
                    longx2 bv = *reinterpret_cast<const longx2*>(&bl[r * BKB + off]);
                    acc[0][ct] = __builtin_amdgcn_mfma_f32_16x16x32_fp8_fp8(
                        af[0][kc][t].x, bv.x, acc[0][ct], 0, 0, 0);
                    acc[1][ct] = __builtin_amdgcn_mfma_f32_16x16x32_fp8_fp8(
                        af[1][kc][t].x, bv.x, acc[1][ct], 0, 0, 0);
                    acc[0][ct] = __builtin_amdgcn_mfma_f32_16x16x32_fp8_fp8(
                        af[0][kc][t].y, bv.y, acc[0][ct], 0, 0, 0);
                    acc[1][ct] = __builtin_amdgcn_mfma_f32_16x16x32_fp8_fp8(
                        af[1][kc][t].y, bv.y, acc[1][ct], 0, 0, 0);
                }
            __builtin_amdgcn_s_setprio(0);
            __builtin_amdgcn_sched_barrier(0);
        }

        // per-n-tile epilogue, register-only (vmcnt counts stay exact).
        // C/D layout: col = lane&15, row = (lane>>4)*4 + reg
        if (EPI == 0) {
#pragma unroll
            for (int rt = 0; rt < 2; ++rt)
#pragma unroll
                for (int reg = 0; reg < 4; ++reg) {
                    float v = 0.f;
#pragma unroll
                    for (int ct = 0; ct < 4; ++ct) v += __expf(acc[rt][ct][reg] * INV_T);
                    vac[rt][reg] += v;
                }
        } else {
#pragma unroll
            for (int rt = 0; rt < 2; ++rt)
#pragma unroll
                for (int reg = 0; reg < 4; ++reg) {
                    float s = Sv[rt][reg];
#pragma unroll
                    for (int ct = 0; ct < 4; ++ct) {
                        float pe = __expf(acc[rt][ct][reg] * INV_T);
                        lsum -= __logf(pe / (pe + s) + EPS_L);
                    }
                }
        }
    }

    if (EPI == 0) {
#pragma unroll
        for (int rt = 0; rt < 2; ++rt)
#pragma unroll
            for (int reg = 0; reg < 4; ++reg) {
                float v = vac[rt][reg];
                v += __shfl_xor(v, 1);
                v += __shfl_xor(v, 2);
                v += __shfl_xor(v, 4);
                v += __shfl_xor(v, 8);
                if (lr == 0)
                    atomicAdd(&S[m0 + wr * 32 + rt * 16 + q * 4 + reg], v);
            }
    } else {
#pragma unroll
        for (int off = 1; off < 64; off <<= 1) lsum += __shfl_xor(lsum, off);
        __syncthreads();
        if (lane == 0) csh[w] = lsum;
        __syncthreads();
        if (tid == 0) {
            float s = 0.f;
#pragma unroll
            for (int i = 0; i < 8; ++i) s += csh[i];
            atomicAdd(loss_sum, s);
        }
    }
}

// ---- gemm0: neg pass ----
__global__ __launch_bounds__(512, 4) void gemm_neg(const fp8_t* __restrict__ A,
                                                   const fp8_t* __restrict__ Bm,
                                                   float* __restrict__ S) {
    __shared__ fp8_t Bl[NBUF][BN * BKB];   // 64 KB ring
    __shared__ float csh[32];
    gemm_body<0, 8>(A, Bm, S, nullptr, blockIdx.y * BM, blockIdx.x * 8,
                    (int)threadIdx.x, Bl, csh);
}

// ---- gemm1 + finalize (last-block arrive) ----
__global__ __launch_bounds__(512, 4) void gemm_pos_fin(
        const fp8_t* __restrict__ A, const fp8_t* __restrict__ Bm,
        float* __restrict__ S, float* __restrict__ lsum,
        const float* __restrict__ csA, const float* __restrict__ csP,
        const float* __restrict__ csN, uint32* __restrict__ cnt,
        float* __restrict__ out) {
    __shared__ fp8_t Bl[NBUF][BN * BKB];
    __shared__ float csh[32];
    __shared__ int lastf;

    const int tid  = threadIdx.x;
    const int lane = tid & 63;
    const int w    = tid >> 6;

    gemm_body<1, 2>(A, Bm, S, lsum, blockIdx.y * BM, blockIdx.x * 2, tid, Bl, csh);

    __syncthreads();
    if (tid == 0) {
        __threadfence();
        uint32 p = atomicAdd(cnt, 1u);
        lastf = (p == GRID - 1);
    }
    __syncthreads();
    if (lastf) {
        __threadfence();
        float av = csA[(size_t)tid * CS_STRIDE];
        float dp = av * csP[(size_t)tid * CS_STRIDE];
        float dn = av * csN[(size_t)tid * CS_STRIDE];
#pragma unroll
        for (int off = 1; off < 64; off <<= 1) {
            dp += __shfl_xor(dp, off);
            dn += __shfl_xor(dn, off);
        }
        float* red = csh;
        __syncthreads();
        if (lane == 0) { red[w] = dp; red[8 + w] = dn; }
        __syncthreads();
        if (tid == 0) {
            float sdp = 0.f, sdn = 0.f;
#pragma unroll
            for (int i = 0; i < 8; ++i) { sdp += red[i]; sdn += red[8 + i]; }
            float mean_pos = sdp * INV_T / ((float)B_ROWS * (float)P_ROWS);
            float mean_neg = sdn * INV_T / ((float)B_ROWS * (float)N_ROWS);
            out[0] = lsum[0] / ((float)B_ROWS * (float)P_ROWS);
            out[1] = mean_pos;
            out[2] = mean_neg;
            out[3] = mean_pos - mean_neg;
        }
    }
}

extern "C" void kernel_launch(void* const* d_in, const int* in_sizes, int n_in,
                              void* d_out, int out_size, void* d_ws, size_t ws_size,
                              hipStream_t stream) {
    const float* anc = (const float*)d_in[0];
    const float* pos = (const float*)d_in[1];
    const float* neg = (const float*)d_in[2];
    float* out = (float*)d_out;

    fp8_t* a8 = (fp8_t*)d_ws;
    fp8_t* p8 = a8 + (size_t)B_ROWS * D_DIM;
    fp8_t* n8 = p8 + (size_t)P_ROWS * D_DIM;
    float* fsec = (float*)(n8 + (size_t)N_ROWS * D_DIM);  // 12MB offset, 64B-aligned
    float* S    = fsec;                        // 4096
    float* csA  = S + B_ROWS;                  // 512*16
    float* csP  = csA + D_DIM * CS_STRIDE;     // 512*16
    float* csN  = csP + D_DIM * CS_STRIDE;     // 512*16
    float* lsum = csN + D_DIM * CS_STRIDE;     // 1 (+3 pad)
    uint32* cnt = (uint32*)(lsum + 4);         // arrive counter

    // ws is re-poisoned 0xAA before every launch -> zero accumulators + counter
    (void)hipMemsetAsync(fsec, 0, (B_ROWS + 3 * D_DIM * CS_STRIDE + 8) * sizeof(float), stream);

    norm_colsum<<<1024, 256, 0, stream>>>(anc, pos, neg, a8, p8, n8, csA, csP, csN);

    gemm_neg<<<dim3((N_ROWS / BN) / 8, B_ROWS / BM), 512, 0, stream>>>(a8, n8, S);
    gemm_pos_fin<<<dim3((P_ROWS / BN) / 2, B_ROWS / BM), 512, 0, stream>>>(
        a8, p8, S, lsum, csA, csP, csN, cnt, out);
}